// Round 1
// baseline (1861.018 us; speedup 1.0000x reference)
//
#include <hip/hip_runtime.h>

typedef __bf16 bf16_t;
typedef __bf16 bf16x8 __attribute__((ext_vector_type(8)));
typedef __bf16 bf16x4 __attribute__((ext_vector_type(4)));
typedef float floatx4 __attribute__((ext_vector_type(4)));

#define D_MODEL 4096
#define SEQ 2048
#define BATCH 2
#define NH 32
#define HD 128
#define AL 10
#define MROWS (BATCH * SEQ)   // 4096
#define N_QKV (3 * D_MODEL)   // 12288

static __device__ __forceinline__ void gload_lds16(const void* g, void* l) {
  __builtin_amdgcn_global_load_lds((const __attribute__((address_space(1))) void*)g,
                                   (__attribute__((address_space(3))) void*)l, 16, 0, 0);
}

// ---------------- fp32 -> bf16 bulk convert ----------------
__global__ void convert_bf16_kernel(const float* __restrict__ src, bf16_t* __restrict__ dst) {
  size_t i = ((size_t)blockIdx.x * 256 + threadIdx.x) * 4;
  float4 v = *(const float4*)(src + i);
  bf16x4 o;
  o[0] = (bf16_t)v.x; o[1] = (bf16_t)v.y; o[2] = (bf16_t)v.z; o[3] = (bf16_t)v.w;
  *(bf16x4*)(dst + i) = o;
}

// ---------------- transpose (D,D) fp32 -> (D,D) bf16 (dst[n][k] = src[k][n]) ----------------
__global__ void transpose_conv_kernel(const float* __restrict__ src, bf16_t* __restrict__ dst) {
  __shared__ float tile[32][33];
  const int tx = threadIdx.x & 31;
  const int ty = threadIdx.x >> 5;
  const int c0 = blockIdx.x * 32;  // source col
  const int r0 = blockIdx.y * 32;  // source row
#pragma unroll
  for (int i = 0; i < 4; i++) {
    int r = ty + i * 8;
    tile[r][tx] = src[(size_t)(r0 + r) * D_MODEL + c0 + tx];
  }
  __syncthreads();
#pragma unroll
  for (int i = 0; i < 4; i++) {
    int r = ty + i * 8;
    dst[(size_t)(c0 + r) * D_MODEL + r0 + tx] = (bf16_t)tile[tx][r];
  }
}

// ---------------- 128x128 tile bf16 MFMA GEMM, B given transposed (Bt[n][k]) ----------------
template <typename OT>
__global__ __launch_bounds__(256) void gemm_bt_kernel(const bf16_t* __restrict__ A,
                                                      const bf16_t* __restrict__ Bt,
                                                      OT* __restrict__ C, int M, int N, int K) {
  __shared__ __align__(16) bf16_t As[128 * 32];
  __shared__ __align__(16) bf16_t Bs[128 * 32];
  const int tid = threadIdx.x;
  const int lane = tid & 63;
  const int wave = tid >> 6;
  const int quad = lane >> 4;
  const int l16 = lane & 15;
  const int m0 = blockIdx.y * 128;
  const int n0 = blockIdx.x * 128;
  const int wm = (wave >> 1) * 64;
  const int wn = (wave & 1) * 64;
  floatx4 acc[4][4] = {};
  for (int k0 = 0; k0 < K; k0 += 32) {
#pragma unroll
    for (int r = 0; r < 2; r++) {
      int c = r * 256 + tid;  // 512 chunks of 16B per tile; row = c>>2, k-quarter = c&3
      gload_lds16(A + (size_t)(m0 + (c >> 2)) * K + k0 + (c & 3) * 8, As + c * 8);
      gload_lds16(Bt + (size_t)(n0 + (c >> 2)) * K + k0 + (c & 3) * 8, Bs + c * 8);
    }
    __syncthreads();
    bf16x8 af[4], bfv[4];
#pragma unroll
    for (int i = 0; i < 4; i++)
      af[i] = *(const bf16x8*)(As + (wm + i * 16 + l16) * 32 + quad * 8);
#pragma unroll
    for (int j = 0; j < 4; j++)
      bfv[j] = *(const bf16x8*)(Bs + (wn + j * 16 + l16) * 32 + quad * 8);
#pragma unroll
    for (int i = 0; i < 4; i++)
#pragma unroll
      for (int j = 0; j < 4; j++)
        acc[i][j] = __builtin_amdgcn_mfma_f32_16x16x32_bf16(af[i], bfv[j], acc[i][j], 0, 0, 0);
    __syncthreads();
  }
#pragma unroll
  for (int i = 0; i < 4; i++)
#pragma unroll
    for (int j = 0; j < 4; j++) {
      int m = m0 + wm + i * 16 + quad * 4;  // + r
      int n = n0 + wn + j * 16 + l16;
#pragma unroll
      for (int r = 0; r < 4; r++) C[(size_t)(m + r) * N + n] = (OT)acc[i][j][r];
    }
}

// ---------------- RoPE in place on Q,K halves of QKV (interleaved pairs) ----------------
__global__ void rope_kernel(bf16_t* __restrict__ QKV, const float* __restrict__ cosb,
                            const float* __restrict__ sinb) {
  int idx = blockIdx.x * 256 + threadIdx.x;  // (row, half, h, i)
  int i = idx & 63;
  int h = (idx >> 6) & 31;
  int half = (idx >> 11) & 1;
  int row = idx >> 12;
  int s = row & (SEQ - 1);
  size_t off = (size_t)row * N_QKV + half * D_MODEL + h * HD + 2 * i;
  float c = cosb[s * 64 + i], sn = sinb[s * 64 + i];
  float x0 = (float)QKV[off], x1 = (float)QKV[off + 1];
  QKV[off] = (bf16_t)(x0 * c - x1 * sn);
  QKV[off + 1] = (bf16_t)(x0 * sn + x1 * c);
}

__global__ void zero_kernel(float* __restrict__ p, int n) {
  int i = blockIdx.x * 256 + threadIdx.x;
  if (i < n) p[i] = 0.f;
}

// ---------------- adapter GEMMs: ak = adapter@wk, av = adapter@wv (fp32) ----------------
__global__ __launch_bounds__(256) void adapter_gemm_kernel(const float* __restrict__ adp,
                                                           const float* __restrict__ wk,
                                                           const float* __restrict__ wv,
                                                           float* __restrict__ ak,
                                                           float* __restrict__ av) {
  const float* W = blockIdx.y ? wv : wk;
  float* out = blockIdx.y ? av : ak;
  const int n = blockIdx.x * 256 + threadIdx.x;
  const int kb = blockIdx.z * 512;
  __shared__ float a_s[AL][512];
  for (int t = threadIdx.x; t < AL * 512; t += 256)
    a_s[t / 512][t % 512] = adp[(t / 512) * D_MODEL + kb + (t % 512)];
  __syncthreads();
  float accv[AL] = {};
  for (int kk = 0; kk < 512; kk++) {
    float w = W[(size_t)(kb + kk) * D_MODEL + n];
#pragma unroll
    for (int a = 0; a < AL; a++) accv[a] += a_s[a][kk] * w;
  }
#pragma unroll
  for (int a = 0; a < AL; a++) atomicAdd(&out[a * D_MODEL + n], accv[a]);
}

// ---------------- flash attention + fused gated adapter attention ----------------
// 1 wave/block, 32-query tile (2 MFMA m-tiles), 32-key tiles.
// MFMA layouts (HW-verified, guide §3): A: m=lane&15,k=quad*8+j; C/D: col=lane&15,row=quad*4+reg.
__global__ __launch_bounds__(64) void flash_kernel(const bf16_t* __restrict__ QKV,
                                                   const float* __restrict__ akp,
                                                   const float* __restrict__ avp,
                                                   const float* __restrict__ gatep,
                                                   bf16_t* __restrict__ Out) {
  const int lane = threadIdx.x;
  const int quad = lane >> 4;
  const int l16 = lane & 15;
  const int q0 = blockIdx.x * 32;
  const int b = blockIdx.y >> 5;
  const int h = blockIdx.y & 31;
  const size_t base = (size_t)b * SEQ * N_QKV;
  const int hoff = h * HD;
  const float scale = 0.08838834764831845f;  // 1/sqrt(128)
  __shared__ __align__(16) bf16_t Pl[2][16][32];

  // Q fragments (A-operand), kept in registers for the whole block
  bf16x8 qa[2][4];
#pragma unroll
  for (int mt = 0; mt < 2; mt++) {
    const bf16_t* qrow = QKV + base + (size_t)(q0 + mt * 16 + l16) * N_QKV + hoff + quad * 8;
#pragma unroll
    for (int c = 0; c < 4; c++) qa[mt][c] = *(const bf16x8*)(qrow + c * 32);
  }
  floatx4 acc[2][8] = {};
  float Mx[2][4], Ls[2][4];
#pragma unroll
  for (int mt = 0; mt < 2; mt++)
#pragma unroll
    for (int r = 0; r < 4; r++) { Mx[mt][r] = -1e30f; Ls[mt][r] = 0.f; }

  for (int j0 = 0; j0 <= q0; j0 += 32) {
    // K fragments (B-operand): n=key(lane&15), k=d(quad*8+j) -> contiguous 16B per lane
    bf16x8 kf[2][4];
#pragma unroll
    for (int nt = 0; nt < 2; nt++) {
      const bf16_t* krow =
          QKV + base + (size_t)(j0 + nt * 16 + l16) * N_QKV + D_MODEL + hoff + quad * 8;
#pragma unroll
      for (int c = 0; c < 4; c++) kf[nt][c] = *(const bf16x8*)(krow + c * 32);
    }
    // V fragments (B-operand for PV): n=d(lane&15 within dtile), k=key(quad*8+jj)
    bf16x8 vf[8];
#pragma unroll
    for (int jj = 0; jj < 8; jj++) {
      const bf16_t* vrow =
          QKV + base + (size_t)(j0 + quad * 8 + jj) * N_QKV + 2 * D_MODEL + hoff + l16;
#pragma unroll
      for (int dt = 0; dt < 8; dt++) vf[dt][jj] = vrow[dt * 16];
    }
    const bool diag = (j0 == q0);
#pragma unroll
    for (int mt = 0; mt < 2; mt++) {
      floatx4 s0 = {}, s1 = {};
#pragma unroll
      for (int c = 0; c < 4; c++) {
        s0 = __builtin_amdgcn_mfma_f32_16x16x32_bf16(qa[mt][c], kf[0][c], s0, 0, 0, 0);
        s1 = __builtin_amdgcn_mfma_f32_16x16x32_bf16(qa[mt][c], kf[1][c], s1, 0, 0, 0);
      }
      const int rowg = q0 + mt * 16 + quad * 4;  // + r
      float alpha[4];
#pragma unroll
      for (int r = 0; r < 4; r++) {
        float v0 = s0[r] * scale;
        float v1 = s1[r] * scale;
        if (diag) {
          if (j0 + l16 > rowg + r) v0 = -1e30f;
          if (j0 + 16 + l16 > rowg + r) v1 = -1e30f;
        }
        float mx = fmaxf(v0, v1);
#pragma unroll
        for (int off = 8; off; off >>= 1) mx = fmaxf(mx, __shfl_xor(mx, off, 64));
        float nm = fmaxf(Mx[mt][r], mx);
        alpha[r] = __expf(Mx[mt][r] - nm);
        Mx[mt][r] = nm;
        float p0 = __expf(v0 - nm);
        float p1 = __expf(v1 - nm);
        float rs = p0 + p1;
#pragma unroll
        for (int off = 8; off; off >>= 1) rs += __shfl_xor(rs, off, 64);
        Ls[mt][r] = Ls[mt][r] * alpha[r] + rs;
        Pl[mt][quad * 4 + r][l16] = (bf16_t)p0;
        Pl[mt][quad * 4 + r][l16 + 16] = (bf16_t)p1;
      }
#pragma unroll
      for (int dt = 0; dt < 8; dt++)
#pragma unroll
        for (int r = 0; r < 4; r++) acc[mt][dt][r] *= alpha[r];
    }
    __syncthreads();  // P writes -> P reads (C-layout -> A-layout transpose via LDS)
#pragma unroll
    for (int mt = 0; mt < 2; mt++) {
      bf16x8 pf = *(const bf16x8*)(&Pl[mt][l16][quad * 8]);
#pragma unroll
      for (int dt = 0; dt < 8; dt++)
        acc[mt][dt] = __builtin_amdgcn_mfma_f32_16x16x32_bf16(pf, vf[dt], acc[mt][dt], 0, 0, 0);
    }
    __syncthreads();  // P reads done before next iteration overwrites
  }

  // ---- gated adapter attention (separate softmax over 10 tokens, no mask) ----
  const float gate = gatep[h];
#pragma unroll
  for (int mt = 0; mt < 2; mt++) {
    floatx4 sa = {};
#pragma unroll
    for (int c = 0; c < 4; c++) {
      bf16x8 bak;
#pragma unroll
      for (int jj = 0; jj < 8; jj++) {
        float v = (l16 < AL) ? akp[(size_t)l16 * D_MODEL + hoff + c * 32 + quad * 8 + jj] : 0.f;
        bak[jj] = (bf16_t)v;
      }
      sa = __builtin_amdgcn_mfma_f32_16x16x32_bf16(qa[mt][c], bak, sa, 0, 0, 0);
    }
#pragma unroll
    for (int r = 0; r < 4; r++) {
      float v = (l16 < AL) ? sa[r] * scale : -1e30f;
      float mx = v;
#pragma unroll
      for (int off = 8; off; off >>= 1) mx = fmaxf(mx, __shfl_xor(mx, off, 64));
      float p = __expf(v - mx);
      float rs = p;
#pragma unroll
      for (int off = 8; off; off >>= 1) rs += __shfl_xor(rs, off, 64);
      float pa = p / rs;
      Pl[mt][quad * 4 + r][l16] = (l16 < AL) ? (bf16_t)pa : (bf16_t)0.f;
      Pl[mt][quad * 4 + r][l16 + 16] = (bf16_t)0.f;
    }
  }
  __syncthreads();
  bf16x8 avf[8];
#pragma unroll
  for (int jj = 0; jj < 8; jj++) {
    int j = quad * 8 + jj;
#pragma unroll
    for (int dt = 0; dt < 8; dt++) {
      float v = (j < AL) ? avp[(size_t)j * D_MODEL + hoff + dt * 16 + l16] : 0.f;
      avf[dt][jj] = (bf16_t)v;
    }
  }
#pragma unroll
  for (int mt = 0; mt < 2; mt++) {
    bf16x8 pf = *(const bf16x8*)(&Pl[mt][l16][quad * 8]);
#pragma unroll
    for (int dt = 0; dt < 8; dt++) {
      floatx4 z = {};
      floatx4 oa = __builtin_amdgcn_mfma_f32_16x16x32_bf16(pf, avf[dt], z, 0, 0, 0);
#pragma unroll
      for (int r = 0; r < 4; r++) {
        int m = q0 + mt * 16 + quad * 4 + r;
        float val = acc[mt][dt][r] / Ls[mt][r] + gate * oa[r];
        Out[(size_t)(b * SEQ + m) * D_MODEL + hoff + dt * 16 + l16] = (bf16_t)val;
      }
    }
  }
}

extern "C" void kernel_launch(void* const* d_in, const int* in_sizes, int n_in, void* d_out,
                              int out_size, void* d_ws, size_t ws_size, hipStream_t stream) {
  const float* x = (const float*)d_in[0];
  const float* cosb = (const float*)d_in[1];
  const float* sinb = (const float*)d_in[2];
  // d_in[3] = mask (causal, implemented analytically)
  const float* wq = (const float*)d_in[4];
  const float* wk = (const float*)d_in[5];
  const float* wv = (const float*)d_in[6];
  const float* wo = (const float*)d_in[7];
  const float* gate = (const float*)d_in[8];
  const float* adp = (const float*)d_in[9];
  // d_in[10] = random_init (always 0 -> non-concat branch)
  float* out = (float*)d_out;

  char* ws = (char*)d_ws;
  const size_t DD = (size_t)D_MODEL * D_MODEL;
  bf16_t* Wt = (bf16_t*)(ws);                  // (3D, K) stacked wq^T,wk^T,wv^T
  bf16_t* Wot = (bf16_t*)(ws + 3 * DD * 2);    // wo^T
  bf16_t* Xb = (bf16_t*)(ws + 4 * DD * 2);     // x as bf16 (M,K)
  bf16_t* QKV = (bf16_t*)(ws + 5 * DD * 2);    // (M, 3D)
  bf16_t* Att = (bf16_t*)(ws + 8 * DD * 2);    // (M, D)
  float* akb = (float*)(ws + 9 * DD * 2);      // (AL, D)
  float* avb = akb + AL * D_MODEL;             // (AL, D)

  convert_bf16_kernel<<<MROWS * D_MODEL / 1024, 256, 0, stream>>>(x, Xb);
  transpose_conv_kernel<<<dim3(128, 128), 256, 0, stream>>>(wq, Wt);
  transpose_conv_kernel<<<dim3(128, 128), 256, 0, stream>>>(wk, Wt + DD);
  transpose_conv_kernel<<<dim3(128, 128), 256, 0, stream>>>(wv, Wt + 2 * DD);
  transpose_conv_kernel<<<dim3(128, 128), 256, 0, stream>>>(wo, Wot);
  gemm_bt_kernel<bf16_t><<<dim3(N_QKV / 128, MROWS / 128), 256, 0, stream>>>(
      Xb, Wt, QKV, MROWS, N_QKV, D_MODEL);
  rope_kernel<<<(MROWS * 4096) / 256, 256, 0, stream>>>(QKV, cosb, sinb);
  zero_kernel<<<(2 * AL * D_MODEL + 255) / 256, 256, 0, stream>>>(akb, 2 * AL * D_MODEL);
  adapter_gemm_kernel<<<dim3(D_MODEL / 256, 2, 8), 256, 0, stream>>>(adp, wk, wv, akb, avb);
  flash_kernel<<<dim3(SEQ / 32, BATCH * NH), 64, 0, stream>>>(QKV, akb, avb, gate, Att);
  gemm_bt_kernel<float><<<dim3(D_MODEL / 128, MROWS / 128), 256, 0, stream>>>(
      Att, Wot, out, MROWS, D_MODEL, D_MODEL);
}